// Round 6
// baseline (230.549 us; speedup 1.0000x reference)
//
#include <hip/hip_runtime.h>
#include <hip/hip_cooperative_groups.h>

namespace cg = cooperative_groups;

#define NN 177
#define NEG 0.2f
#define QR 45                 // dst rows per quarter (last quarter uses 42)
#define QSLOTS (QR * NN)      // 7965
#define SL 8064               // padded partial slice (QSLOTS + QR -> 8064)
#define NCHUNK 128
#define EBLOCKS (NCHUNK * 4)  // 512 blocks
#define ETH 512               // threads per block
#define NGROUP 8
#define CPG (NCHUNK / NGROUP) // 16

// workspace layout (floats)
#define AI_OFF   0
#define AJ_OFF   192
#define G_OFF    384
#define PART_OFF 23040                       // 512 slices of SL (~16.5 MB)
#define RED8_OFF (PART_OFF + EBLOCKS * SL)   // 258048 floats (~1 MB)

__global__ __launch_bounds__(ETH, 2)
void kfused(const float* __restrict__ x, const float* __restrict__ ea,
            const float* __restrict__ w, const float* __restrict__ att,
            const float* __restrict__ eu, const float* __restrict__ bias,
            const int* __restrict__ ei, float* __restrict__ out,
            float* __restrict__ ws, int E, int CH) {
    cg::grid_group grid = cg::this_grid();
    __shared__ float Wl[QSLOTS];
    __shared__ float ajl[NN], ailq[QR], Mq[QR], llast[QR];
    const int tid = threadIdx.x;
    const int bid = blockIdx.x;

    // ---- Phase 1: node transform (blocks 0..176) ----
    if (bid < NN) {
        float* xl = Wl;            // 128
        float* hl = Wl + 128;      // 128
        float* ph = Wl + 256;      // 512
        float* r0 = Wl + 768;      // 128
        float* r1 = Wl + 896;      // 128
        const int n = bid, c = tid & 127, qk = tid >> 7;
        if (tid < 128) xl[tid] = x[n * 128 + tid];
        __syncthreads();
        float a = 0.f;
        const float* wp = w + (size_t)(qk * 32) * 128 + c;
#pragma unroll 8
        for (int k = 0; k < 32; ++k) a += xl[qk * 32 + k] * wp[(size_t)k * 128];
        ph[tid] = a;
        __syncthreads();
        if (tid < 128) {
            float hv = ph[tid] + ph[tid + 128] + ph[tid + 256] + ph[tid + 384];
            hl[tid] = hv;
            r0[tid] = hv * att[tid];
            r1[tid] = hv * att[128 + tid];
        }
        __syncthreads();
        for (int off = 64; off > 0; off >>= 1) {
            if (tid < off) { r0[tid] += r0[tid + off]; r1[tid] += r1[tid + off]; }
            __syncthreads();
        }
        if (tid == 0) { ws[AI_OFF + n] = r0[0]; ws[AJ_OFF + n] = r1[0]; }
        float b = 0.f;
        const float* ep = eu + (size_t)(qk * 32) * 128 + c;
#pragma unroll 8
        for (int k = 0; k < 32; ++k) b += hl[qk * 32 + k] * ep[(size_t)k * 128];
        __syncthreads();
        ph[tid] = b;
        __syncthreads();
        if (tid < 128) ws[G_OFF + n * 128 + tid] = ph[tid] + ph[tid + 128] + ph[tid + 256] + ph[tid + 384];
    }
    grid.sync();

    // ---- Phase 2: edge pass (all 512 blocks; chunk = bid>>2, quarter = bid&3) ----
    {
        const int chunk = bid >> 2, q = bid & 3;
        const int dlo = q * QR;
        int drows = NN - dlo; if (drows > QR) drows = QR;
        for (int i = tid; i < QSLOTS; i += ETH) Wl[i] = 0.f;
        for (int i = tid; i < NN; i += ETH) ajl[i] = ws[AJ_OFF + i];
        if (tid < QR) llast[tid] = 0.f;
        __syncthreads();
        float ajmax = -1e30f;
        for (int i = 0; i < NN; ++i) ajmax = fmaxf(ajmax, ajl[i]);
        if (tid < drows) {
            float a = ws[AI_OFF + dlo + tid];
            ailq[tid] = a;
            float M = a + ajmax + 1.0f;          // safe softmax shift (shift-invariant)
            Mq[tid] = (M > 0.f) ? M : NEG * M;
        }
        const float cc = att[2 * 128];
        __syncthreads();

        const int base = chunk * CH;
        int lim = base + CH; if (lim > E) lim = E;
        const bool aligned4 = ((E & 3) == 0);
        for (int e0 = base + tid * 4; e0 < lim; e0 += ETH * 4) {
            int4 sv, dv; float4 eav;
            if (aligned4 && e0 + 3 < lim) {
                sv  = *(const int4*)(ei + e0);
                dv  = *(const int4*)(ei + E + e0);
                eav = *(const float4*)(ea + e0);
            } else {
                int e1 = lim - e0;
                sv.x = (e1 > 0) ? ei[e0]     : 0; dv.x = (e1 > 0) ? ei[E + e0]     : -1; eav.x = (e1 > 0) ? ea[e0]     : 0.f;
                sv.y = (e1 > 1) ? ei[e0 + 1] : 0; dv.y = (e1 > 1) ? ei[E + e0 + 1] : -1; eav.y = (e1 > 1) ? ea[e0 + 1] : 0.f;
                sv.z = (e1 > 2) ? ei[e0 + 2] : 0; dv.z = (e1 > 2) ? ei[E + e0 + 2] : -1; eav.z = (e1 > 2) ? ea[e0 + 2] : 0.f;
                sv.w = (e1 > 3) ? ei[e0 + 3] : 0; dv.w = (e1 > 3) ? ei[E + e0 + 3] : -1; eav.w = (e1 > 3) ? ea[e0 + 3] : 0.f;
            }
#define PROC(SS, DD, EE) do {                                   \
                int d_ = (DD) - dlo;                            \
                if ((unsigned)d_ < (unsigned)drows) {           \
                    float t_ = ailq[d_] + ajl[SS] + cc * (EE);  \
                    t_ = (t_ > 0.f) ? t_ : NEG * t_;            \
                    float ev_ = __expf(t_ - Mq[d_]);            \
                    atomicAdd(&Wl[d_ * NN + (SS)], ev_);        \
                    atomicAdd(&llast[d_], ev_ * (EE));          \
                }                                               \
            } while (0)
            PROC(sv.x, dv.x, eav.x);
            PROC(sv.y, dv.y, eav.y);
            PROC(sv.z, dv.z, eav.z);
            PROC(sv.w, dv.w, eav.w);
#undef PROC
        }
        __syncthreads();
        float* part = ws + PART_OFF + (size_t)bid * SL;
        for (int i = tid; i < QSLOTS; i += ETH) part[i] = Wl[i];
        if (tid < QR) part[QSLOTS + tid] = (tid < drows) ? llast[tid] : 0.f;
    }
    grid.sync();

    // ---- Phase 3: reduce 128 chunks -> 8 groups (blocks 0..503) ----
    {
        int gid = bid * ETH + tid;
        if (gid < NGROUP * 4 * SL) {
            int g = gid / (4 * SL);
            int rem = gid - g * (4 * SL);
            const float* part = ws + PART_OFF;
            float acc = 0.f;
#pragma unroll
            for (int k = 0; k < CPG; ++k)
                acc += part[(size_t)(g * CPG + k) * (4 * SL) + rem];
            ws[RED8_OFF + gid] = acc;
        }
    }
    grid.sync();

    // ---- Phase 4: final reduce + output (blocks 0..176) ----
    if (bid < NN) {
        float* wl  = Wl;            // 177
        float* red = Wl + 256;      // 128
        float* pd  = Wl + 512;      // 512
        float* w8  = Wl + 1100;     // 8
        const int n = bid, q = n / QR, r = n % QR;
        const float* r8 = ws + RED8_OFF + (size_t)q * SL;
        if (tid < NN) {
            float acc = 0.f;
#pragma unroll
            for (int g = 0; g < NGROUP; ++g)
                acc += r8[(size_t)g * (4 * SL) + r * NN + tid];
            wl[tid] = acc;
        }
        if (tid < NGROUP) w8[tid] = r8[(size_t)tid * (4 * SL) + QSLOTS + r];
        __syncthreads();
        if (tid < 128) red[tid] = wl[tid] + ((tid + 128 < NN) ? wl[tid + 128] : 0.f);
        __syncthreads();
        for (int off = 64; off > 0; off >>= 1) {
            if (tid < off) red[tid] += red[tid + off];
            __syncthreads();
        }
        const float ssum = red[0];
        const float wlast_n = ((w8[0] + w8[1]) + (w8[2] + w8[3])) +
                              ((w8[4] + w8[5]) + (w8[6] + w8[7]));
        const int c = tid & 127, sg = tid >> 7;
        int slo = sg * 45, shi = slo + 45; if (shi > NN) shi = NN;
        const float* G = ws + G_OFF;
        float acc = 0.f;
        for (int s = slo; s < shi; ++s) acc += wl[s] * G[s * 128 + c];
        pd[tid] = acc;
        __syncthreads();
        if (tid < 128) {
            float dot = pd[tid] + pd[tid + 128] + pd[tid + 256] + pd[tid + 384];
            out[n * 128 + tid] = (dot + wlast_n * eu[128 * 128 + tid]) / (ssum + 1e-16f) + bias[tid];
        }
    }
}

extern "C" void kernel_launch(void* const* d_in, const int* in_sizes, int n_in,
                              void* d_out, int out_size, void* d_ws, size_t ws_size,
                              hipStream_t stream) {
    const float* x     = (const float*)d_in[0];
    const float* eattr = (const float*)d_in[1];
    const float* w     = (const float*)d_in[2];
    const float* att   = (const float*)d_in[3];
    const float* eu    = (const float*)d_in[4];
    const float* bias  = (const float*)d_in[5];
    const int*   ei    = (const int*)d_in[6];
    int E = in_sizes[6] / 2;
    int CH = (((E + NCHUNK - 1) / NCHUNK) + 3) & ~3;
    float* ws = (float*)d_ws;
    float* out = (float*)d_out;

    void* args[] = { (void*)&x, (void*)&eattr, (void*)&w, (void*)&att, (void*)&eu,
                     (void*)&bias, (void*)&ei, (void*)&out, (void*)&ws, (void*)&E, (void*)&CH };
    hipLaunchCooperativeKernel((void*)kfused, dim3(EBLOCKS), dim3(ETH), args, 0, stream);
}

// Round 7
// 58.439 us; speedup vs baseline: 3.9451x; 3.9451x over previous
//
#include <hip/hip_runtime.h>

#define NN 177
#define NEG 0.2f
#define QR 45                 // dst rows per quarter (last quarter 42)
#define QSLOTS (QR * NN)      // 7965
#define SL 8064               // padded partial slice
#define NCHUNK 128
#define EBLOCKS (NCHUNK * 4)  // 512
#define ETH 512

// workspace layout (floats)
#define G_OFF    384
#define PART_OFF 23040        // 512 slices of SL (~16.5 MB)

// Kernel A: self-contained edge pass.
//  - u = W@att0, v = W@att1 (per-block, float4 + wave shuffle reduce)
//  - ai[n] = x[n]·u, aj[n] = x[n]·v  (associativity: == (x@W)·att)
//  - blocks 0..176 also emit G row n = (x[n]@W)@eu
//  - LDS-private W-quarter edge accumulation, partial flush
__global__ __launch_bounds__(ETH)
void k_edgeA(const float* __restrict__ x, const float* __restrict__ ea,
             const float* __restrict__ w, const float* __restrict__ att,
             const float* __restrict__ eu, const int* __restrict__ ei,
             float* __restrict__ ws, int E, int CH) {
    __shared__ float Wl[QSLOTS];
    __shared__ float ajl[NN], ail[NN], Mq[QR], llast[QR];
    __shared__ float uvec[128], vvec[128], atl[257];
    const int tid = threadIdx.x;
    const int bid = blockIdx.x;

    for (int i = tid; i < 257; i += ETH) atl[i] = att[i];
    __syncthreads();

    // ---- u, v ----
#pragma unroll
    for (int i = 0; i < 8; ++i) {
        int flat = i * 2048 + tid * 4;
        int k = flat >> 7, c = flat & 127;
        float4 wv = *(const float4*)(w + flat);
        float pu = wv.x*atl[c]     + wv.y*atl[c+1]     + wv.z*atl[c+2]     + wv.w*atl[c+3];
        float pv = wv.x*atl[128+c] + wv.y*atl[128+c+1] + wv.z*atl[128+c+2] + wv.w*atl[128+c+3];
#pragma unroll
        for (int m = 1; m <= 16; m <<= 1) {
            pu += __shfl_xor(pu, m);
            pv += __shfl_xor(pv, m);
        }
        if ((tid & 31) == 0) { uvec[k] = pu; vvec[k] = pv; }
    }
    __syncthreads();

    // ---- ai, aj ----
    if (tid < 2 * NN) {
        int n = tid % NN, half = tid / NN;
        const float* xr = x + n * 128 + half * 64;
        const float* ur = uvec + half * 64;
        const float* vr = vvec + half * 64;
        float pa = 0.f, pb = 0.f;
#pragma unroll 8
        for (int k = 0; k < 64; ++k) { float xv = xr[k]; pa += xv * ur[k]; pb += xv * vr[k]; }
        Wl[tid] = pa; Wl[512 + tid] = pb;
    }
    __syncthreads();
    if (tid < NN) {
        ail[tid] = Wl[tid] + Wl[NN + tid];
        ajl[tid] = Wl[512 + tid] + Wl[512 + NN + tid];
    }
    __syncthreads();

    // ---- blocks 0..176: h row + G row ----
    if (bid < NN) {
        float* ph = Wl + 1024;
        float* xl = Wl + 1536;
        float* hl = Wl + 1664;
        if (tid < 128) xl[tid] = x[bid * 128 + tid];
        __syncthreads();
        const int c = tid & 127, kg = tid >> 7;
        const float* wp = w + (size_t)(kg * 32) * 128 + c;
        float a = 0.f;
#pragma unroll 8
        for (int k = 0; k < 32; ++k) a += xl[kg * 32 + k] * wp[(size_t)k * 128];
        ph[tid] = a;
        __syncthreads();
        if (tid < 128) hl[tid] = ph[tid] + ph[tid+128] + ph[tid+256] + ph[tid+384];
        __syncthreads();
        const float* ep = eu + (size_t)(kg * 32) * 128 + c;
        float b = 0.f;
#pragma unroll 8
        for (int k = 0; k < 32; ++k) b += hl[kg * 32 + k] * ep[(size_t)k * 128];
        ph[tid] = b;
        __syncthreads();
        if (tid < 128)
            ws[G_OFF + bid * 128 + tid] = ph[tid] + ph[tid+128] + ph[tid+256] + ph[tid+384];
        __syncthreads();
    }

    // ---- edge pass setup ----
    const int chunk = bid >> 2, q = bid & 3;
    const int dlo = q * QR;
    int drows = NN - dlo; if (drows > QR) drows = QR;
    float ajmax = -1e30f;
    for (int i = 0; i < NN; ++i) ajmax = fmaxf(ajmax, ajl[i]);
    for (int i = tid; i < QSLOTS; i += ETH) Wl[i] = 0.f;
    if (tid < QR) llast[tid] = 0.f;
    if (tid < drows) {
        float M = ail[dlo + tid] + ajmax + 1.0f;   // safe shift (softmax shift-invariant)
        Mq[tid] = (M > 0.f) ? M : NEG * M;
    }
    const float cc = atl[256];
    __syncthreads();

    // ---- edge loop ----
    const int base = chunk * CH;
    int lim = base + CH; if (lim > E) lim = E;
    const bool aligned4 = ((E & 3) == 0);
    for (int e0 = base + tid * 4; e0 < lim; e0 += ETH * 4) {
        int4 sv, dv; float4 eav;
        if (aligned4 && e0 + 3 < lim) {
            sv  = *(const int4*)(ei + e0);
            dv  = *(const int4*)(ei + E + e0);
            eav = *(const float4*)(ea + e0);
        } else {
            int e1 = lim - e0;
            sv.x = (e1 > 0) ? ei[e0]     : 0; dv.x = (e1 > 0) ? ei[E + e0]     : -1; eav.x = (e1 > 0) ? ea[e0]     : 0.f;
            sv.y = (e1 > 1) ? ei[e0 + 1] : 0; dv.y = (e1 > 1) ? ei[E + e0 + 1] : -1; eav.y = (e1 > 1) ? ea[e0 + 1] : 0.f;
            sv.z = (e1 > 2) ? ei[e0 + 2] : 0; dv.z = (e1 > 2) ? ei[E + e0 + 2] : -1; eav.z = (e1 > 2) ? ea[e0 + 2] : 0.f;
            sv.w = (e1 > 3) ? ei[e0 + 3] : 0; dv.w = (e1 > 3) ? ei[E + e0 + 3] : -1; eav.w = (e1 > 3) ? ea[e0 + 3] : 0.f;
        }
#define PROC(SS, DD, EE) do {                                   \
            int d_ = (DD) - dlo;                                \
            if ((unsigned)d_ < (unsigned)drows) {               \
                float t_ = ail[dlo + d_] + ajl[SS] + cc * (EE); \
                t_ = (t_ > 0.f) ? t_ : NEG * t_;                \
                float ev_ = __expf(t_ - Mq[d_]);                \
                atomicAdd(&Wl[d_ * NN + (SS)], ev_);            \
                atomicAdd(&llast[d_], ev_ * (EE));              \
            }                                                   \
        } while (0)
        PROC(sv.x, dv.x, eav.x);
        PROC(sv.y, dv.y, eav.y);
        PROC(sv.z, dv.z, eav.z);
        PROC(sv.w, dv.w, eav.w);
#undef PROC
    }
    __syncthreads();
    float* part = ws + PART_OFF + (size_t)bid * SL;
    for (int i = tid; i < QSLOTS; i += ETH) part[i] = Wl[i];
    if (tid < QR) part[QSLOTS + tid] = (tid < drows) ? llast[tid] : 0.f;
}

// Kernel B: fused 128-chunk reduce + wlast + rowsum + output matmul.
__global__ __launch_bounds__(ETH)
void k_outB(const float* __restrict__ ws, const float* __restrict__ eu,
            const float* __restrict__ bias, float* __restrict__ out) {
    __shared__ float wl[NN];
    __shared__ float pd[ETH];
    __shared__ float red[128];
    const int n = blockIdx.x, tid = threadIdx.x;
    const int q = n / QR, r = n % QR;
    const float* base = ws + PART_OFF + (size_t)q * SL + (size_t)r * NN;

    // W row n: sum over 128 chunks, 2-way chunk split per s
    {
        const int cg = tid >> 8, s = tid & 255;
        float acc = 0.f;
        if (s < NN) {
            const float* p = base + (size_t)(cg * 64) * (4 * SL) + s;
#pragma unroll 8
            for (int ch = 0; ch < 64; ++ch)
                acc += p[(size_t)ch * (4 * SL)];
        }
        pd[tid] = acc;
    }
    __syncthreads();
    if (tid < NN) wl[tid] = pd[tid] + pd[256 + tid];

    // wlast: one value per chunk
    if (tid < 128) red[tid] = ws[PART_OFF + (size_t)(tid * 4 + q) * SL + QSLOTS + r];
    __syncthreads();
    for (int off = 64; off > 0; off >>= 1) {
        if (tid < off) red[tid] += red[tid + off];
        __syncthreads();
    }
    const float wlast_n = red[0];
    __syncthreads();

    // rowsum (softmax denominator)
    if (tid < 128) red[tid] = wl[tid] + ((tid + 128 < NN) ? wl[tid + 128] : 0.f);
    __syncthreads();
    for (int off = 64; off > 0; off >>= 1) {
        if (tid < off) red[tid] += red[tid + off];
        __syncthreads();
    }
    const float ssum = red[0];

    // out[n][c] = (wl·G[:,c] + wlast*eu_last[c]) / ssum + bias[c]
    const float* G = ws + G_OFF;
    const int c = tid & 127, sg = tid >> 7;
    int slo = sg * 45, shi = slo + 45; if (shi > NN) shi = NN;
    float acc = 0.f;
    for (int s = slo; s < shi; ++s) acc += wl[s] * G[s * 128 + c];
    pd[tid] = acc;
    __syncthreads();
    if (tid < 128) {
        float dot = pd[tid] + pd[tid + 128] + pd[tid + 256] + pd[tid + 384];
        out[n * 128 + tid] = (dot + wlast_n * eu[128 * 128 + tid]) / (ssum + 1e-16f) + bias[tid];
    }
}

extern "C" void kernel_launch(void* const* d_in, const int* in_sizes, int n_in,
                              void* d_out, int out_size, void* d_ws, size_t ws_size,
                              hipStream_t stream) {
    const float* x     = (const float*)d_in[0];
    const float* eattr = (const float*)d_in[1];
    const float* w     = (const float*)d_in[2];
    const float* att   = (const float*)d_in[3];
    const float* eu    = (const float*)d_in[4];
    const float* bias  = (const float*)d_in[5];
    const int*   ei    = (const int*)d_in[6];
    int E = in_sizes[6] / 2;
    int CH = (((E + NCHUNK - 1) / NCHUNK) + 3) & ~3;
    float* ws = (float*)d_ws;

    k_edgeA<<<EBLOCKS, ETH, 0, stream>>>(x, eattr, w, att, eu, ei, ws, E, CH);
    k_outB<<<NN, ETH, 0, stream>>>(ws, eu, bias, (float*)d_out);
}